// Round 1
// baseline (374.656 us; speedup 1.0000x reference)
//
#include <hip/hip_runtime.h>

#define H 1024
#define W 1024
#define KS 21
#define RAD 10
#define TX 64
#define TY 64
#define HROWS (TY + 2 * RAD)   // 84 h-filtered rows per tile
#define LSTRIDE 65             // +1 pad: phase-2 column reads conflict-free
#define SEGW 16                // h-outputs per job (register sliding window)
#define NSEG (TX / SEGW)       // 4
#define NJOBS (HROWS * NSEG)   // 336 -> 256 threads do 1-2 jobs each
#define OUTS 16                // phase-2 outputs per thread (4 wavegroups x 16 = 64 rows)

// jnp 'reflect' (no edge repeat) for indices in [-(W-1), 2W-2]
__device__ __forceinline__ int reflect1024(int i) {
    return 1023 - abs(1023 - abs(i));
}

__global__ __launch_bounds__(256)
void gauss_fused(const float* __restrict__ in, const float* __restrict__ k2d,
                 float* __restrict__ out) {
    __shared__ float hbuf[HROWS][LSTRIDE];   // 84*65*4 = 21840 B -> ~7 blocks/CU by LDS
    __shared__ float rw_s[KS];

    const int tid = threadIdx.x;
    const int x0 = blockIdx.x * TX;
    const int y0 = blockIdx.y * TY;
    const long long plane = (long long)blockIdx.z * (long long)(H * W);
    const float* inp = in + plane;

    // separable 1D factor: k2d = outer(r,r), r[i] = k2d[i][c]/sqrt(k2d[c][c])
    if (tid < KS) {
        float c = k2d[RAD * KS + RAD];
        rw_s[tid] = k2d[tid * KS + RAD] / sqrtf(c);
    }
    __syncthreads();

    float w[KS];
#pragma unroll
    for (int j = 0; j < KS; ++j) w[j] = rw_s[j];

    // ---- Phase 1: horizontal conv, register sliding window, 16 outputs/job ----
    const bool xint = (x0 != 0) && (x0 != W - TX);

    // NOT unrolled: emit the big body exactly once (code size / I$)
#pragma unroll 1
    for (int job = tid; job < NJOBS; job += 256) {
        const int row = job >> 2;    // 0..83
        const int seg = job & 3;
        const int gy = reflect1024(y0 + row - RAD);
        const float* rowp = inp + (long long)gy * W;
        const int xs = x0 + seg * SEGW - RAD;  // first tap x of output 0

        if (xint) {
            // xs-2 is 16B-aligned (x0%64==0, seg*16-12 ≡ 0 mod 4)
            float win[40];
            const float4* p4 = (const float4*)(rowp + (xs - 2));
#pragma unroll
            for (int q = 0; q < 10; ++q) {
                const float4 vq = p4[q];
                win[4 * q + 0] = vq.x; win[4 * q + 1] = vq.y;
                win[4 * q + 2] = vq.z; win[4 * q + 3] = vq.w;
            }
#pragma unroll
            for (int i = 0; i < SEGW; ++i) {
                float s = 0.f;
#pragma unroll
                for (int j = 0; j < KS; ++j) s += w[j] * win[2 + i + j];
                hbuf[row][seg * SEGW + i] = s;
            }
        } else {
            float win[36];
#pragma unroll
            for (int q = 0; q < 36; ++q) win[q] = rowp[reflect1024(xs + q)];
#pragma unroll
            for (int i = 0; i < SEGW; ++i) {
                float s = 0.f;
#pragma unroll
                for (int j = 0; j < KS; ++j) s += w[j] * win[i + j];
                hbuf[row][seg * SEGW + i] = s;
            }
        }
    }
    __syncthreads();

    // ---- Phase 2: vertical conv as a pure-gather with all-compile-time taps ----
    // Read the 36 column samples once into registers, then 16 outputs x 21 FMA.
    // No conditional scatter, no dynamically-indexed arrays -> guaranteed fold.
    const int tx = tid & 63;
    const int wg = tid >> 6;          // 0..3
    const int rbase = wg * OUTS;      // output rows y0+rbase .. +15

    float v[OUTS + KS - 1];           // 36
#pragma unroll
    for (int r = 0; r < OUTS + KS - 1; ++r) v[r] = hbuf[rbase + r][tx];

    float* outp = out + plane;
#pragma unroll
    for (int yo = 0; yo < OUTS; ++yo) {
        float s = 0.f;
#pragma unroll
        for (int j = 0; j < KS; ++j) s += w[j] * v[yo + j];
        outp[(long long)(y0 + rbase + yo) * W + (x0 + tx)] = s;
    }
}

extern "C" void kernel_launch(void* const* d_in, const int* in_sizes, int n_in,
                              void* d_out, int out_size, void* d_ws, size_t ws_size,
                              hipStream_t stream) {
    const float* x = (const float*)d_in[0];
    const float* k = (const float*)d_in[1];
    float* out = (float*)d_out;
    const int n = in_sizes[0] / (H * W);  // batch*channels = 32
    dim3 grid(W / TX, H / TY, n);
    gauss_fused<<<grid, dim3(256), 0, stream>>>(x, k, out);
}

// Round 2
// 274.350 us; speedup vs baseline: 1.3656x; 1.3656x over previous
//
#include <hip/hip_runtime.h>

#define H 1024
#define W 1024
#define KS 21
#define RAD 10
#define TX 64
#define TY 44
#define HROWS (TY + 2 * RAD)   // 64 h-filtered rows needed per tile
#define RS 89                  // raw row stride in floats (odd -> conflict-free windows)
#define RCOLS 88               // staged cols: x0-12 .. x0+75 (16B-aligned float4 start)
#define NYT ((H + TY - 1) / TY)  // 24 y-tiles (last one partially stored)

// jnp 'reflect' (no edge repeat) for indices in [-(W-1), 2W-2]
__device__ __forceinline__ int reflect1024(int i) {
    return 1023 - abs(1023 - abs(i));
}

__global__ __launch_bounds__(256)
void gauss_fused(const float* __restrict__ in, const float* __restrict__ k2d,
                 float* __restrict__ out) {
    // Single LDS buffer, used twice:
    //   phase 0/1: raw input tile [64 rows][cols x0-12 .. x0+75]
    //   phase 1b : h-conv results overwrite cols 0..63 (after a barrier)
    __shared__ float raw[HROWS][RS];   // 64*89*4 = 22784 B -> 7 blocks/CU by LDS
    __shared__ float rw_s[KS];

    const int tid = threadIdx.x;
    const int x0 = blockIdx.x * TX;
    const int y0 = blockIdx.y * TY;
    const long long plane = (long long)blockIdx.z * (long long)(H * W);
    const float* inp = in + plane;

    // separable 1D factor: k2d = outer(r,r), r[i] = k2d[i][c]/sqrt(k2d[c][c])
    if (tid < KS) {
        float c = k2d[RAD * KS + RAD];
        rw_s[tid] = k2d[tid * KS + RAD] / sqrtf(c);
    }
    __syncthreads();

    float w[KS];
#pragma unroll
    for (int j = 0; j < KS; ++j) w[j] = rw_s[j];

    // ---- Phase 0: stage raw tile into LDS, wave-coalesced ----
    // Interior-x blocks: float4 loads of cols x0-12 .. x0+75 (aligned: (x0-12)*4 % 16 == 0).
    const bool xint = (x0 != 0) && (x0 != W - TX);
    if (xint) {
#pragma unroll 1
        for (int idx = tid; idx < HROWS * 22; idx += 256) {   // 1408 float4 jobs
            const int row = idx / 22;
            const int q = idx - row * 22;
            const int gy = reflect1024(y0 + row - RAD);
            const float4 v = *((const float4*)(inp + (long long)gy * W + (x0 - 12)) + q);
            const int c = 4 * q;
            raw[row][c + 0] = v.x; raw[row][c + 1] = v.y;
            raw[row][c + 2] = v.z; raw[row][c + 3] = v.w;
        }
    } else {
        // x-edge blocks: scalar loads, still wave-coalesced (consecutive c -> consecutive addr)
#pragma unroll 1
        for (int idx = tid; idx < HROWS * RCOLS; idx += 256) { // 5632 jobs = 22 iters
            const int row = idx / RCOLS;
            const int c = idx - row * RCOLS;
            const int gy = reflect1024(y0 + row - RAD);
            raw[row][c] = inp[(long long)gy * W + reflect1024(x0 - 12 + c)];
        }
    }
    __syncthreads();

    // ---- Phase 1: horizontal conv — exactly one job per thread ----
    // job: row hr = tid>>2 (0..63), seg hs = tid&3 (16 outputs each).
    // out col c uses raw cols c+2 .. c+22  (raw col 0 == x0-12).
    // Bank check: addr = 89*hr + 16*hs + 2 + q -> 25*hr + 16*hs mod 32: 2-way only (free).
    const int hr = tid >> 2;
    const int hs = tid & 3;
    float win[36];
#pragma unroll
    for (int q = 0; q < 36; ++q) win[q] = raw[hr][16 * hs + 2 + q];

    float hacc[16];
#pragma unroll
    for (int i = 0; i < 16; ++i) {
        float s = 0.f;
#pragma unroll
        for (int j = 0; j < KS; ++j) s += w[j] * win[i + j];
        hacc[i] = s;
    }
    __syncthreads();          // all window reads complete before in-place overwrite
#pragma unroll
    for (int i = 0; i < 16; ++i) raw[hr][16 * hs + i] = hacc[i];
    __syncthreads();

    // ---- Phase 2: vertical conv — thread (tx, wg) does 11 output rows ----
    // reads raw[rbase+q][tx]: lanes tx consecutive -> conflict-free; stores coalesced.
    const int tx = tid & 63;
    const int wg = tid >> 6;
    const int rbase = wg * 11;     // 4 * 11 = 44 output rows

    float v[11 + KS - 1];          // 31 column samples
#pragma unroll
    for (int q = 0; q < 31; ++q) v[q] = raw[rbase + q][tx];

    float* outp = out + plane;
#pragma unroll
    for (int yo = 0; yo < 11; ++yo) {
        float s = 0.f;
#pragma unroll
        for (int j = 0; j < KS; ++j) s += w[j] * v[yo + j];
        const int gy = y0 + rbase + yo;
        if (gy < H) outp[(long long)gy * W + (x0 + tx)] = s;
    }
}

extern "C" void kernel_launch(void* const* d_in, const int* in_sizes, int n_in,
                              void* d_out, int out_size, void* d_ws, size_t ws_size,
                              hipStream_t stream) {
    const float* x = (const float*)d_in[0];
    const float* k = (const float*)d_in[1];
    float* out = (float*)d_out;
    const int n = in_sizes[0] / (H * W);  // batch*channels = 32
    dim3 grid(W / TX, NYT, n);
    gauss_fused<<<grid, dim3(256), 0, stream>>>(x, k, out);
}

// Round 3
// 249.107 us; speedup vs baseline: 1.5040x; 1.1013x over previous
//
#include <hip/hip_runtime.h>

#define H 1024
#define W 1024
#define KS 21
#define RAD 10
#define TX 224            // output cols per block (halo: stage 256 cols, 1/thread)
#define NXB 5             // ceil(1024/224); last block masks cols >= 1024
#define YO 128            // output rows per block
#define R 8               // rows per step
#define NSTEP (YO / R)    // 16
#define LSTR 257          // LDS row stride in floats (bank spread: 257 % 32 = 1)
#define WIN (KS + R - 1)  // 28-deep vertical register window

// jnp 'reflect' (no edge repeat) for indices in [-(W-1), 2W-2]
__device__ __forceinline__ int reflect1024(int i) {
    return 1023 - abs(1023 - abs(i));
}

__global__ __launch_bounds__(256, 5)
void gauss_fused(const float* __restrict__ in, const float* __restrict__ k2d,
                 float* __restrict__ out) {
    __shared__ float vbuf[R][LSTR];   // v-conv results, col j = global col x0-12+j
    __shared__ float hbuf[R][LSTR];   // h-conv results, col j = global col x0+j
    __shared__ float rw_s[KS];        // 2*8*257*4 + 84 = 16532 B

    const int t = threadIdx.x;
    const int x0 = blockIdx.x * TX;
    const int y0 = blockIdx.y * YO;
    const long long plane = (long long)blockIdx.z * (long long)(H * W);
    const float* inp = in + plane;
    float* outp = out + plane;

    // separable 1D factor: k2d = outer(r,r), r[i] = k2d[i][c]/sqrt(k2d[c][c])
    if (t < KS) {
        float c = k2d[RAD * KS + RAD];
        rw_s[t] = k2d[t * KS + RAD] / sqrtf(c);
    }
    __syncthreads();

    // force weights into SGPRs (wave-uniform): v_fma can take 1 SGPR operand
    float w[KS];
#pragma unroll
    for (int j = 0; j < KS; ++j)
        w[j] = __uint_as_float(__builtin_amdgcn_readfirstlane(__float_as_uint(rw_s[j])));

    // per-thread fixed input column (x-reflect folded in once); lane t -> col x0-12+t
    // interior blocks: consecutive lanes = consecutive addrs, 16B-aligned base
    const int xc = reflect1024(x0 - 12 + t);
    const float* colp = inp + xc;

    // ---- preload vertical window: rows y0-10 .. y0+9, prefetch y0+10 .. y0+17 ----
    float win[WIN];
#pragma unroll
    for (int q = 0; q < WIN - R; ++q)            // 20 rows
        win[q] = colp[reflect1024(y0 - RAD + q) << 10];
    float pf[R];
#pragma unroll
    for (int j = 0; j < R; ++j)
        pf[j] = colp[reflect1024(y0 + RAD + j) << 10];

#pragma unroll 1
    for (int s = 0; s < NSTEP; ++s) {
        // complete the window from last step's prefetch
#pragma unroll
        for (int j = 0; j < R; ++j) win[20 + j] = pf[j];

        // issue next step's loads NOW — ~2 barriers of compute hide the latency
        if (s < NSTEP - 1) {
            const int nbase = y0 + 8 * s + 18;   // rows ys+10 .. ys+17 of next step
#pragma unroll
            for (int j = 0; j < R; ++j)
                pf[j] = colp[reflect1024(nbase + j) << 10];
        }

        // ---- v-conv: 8 outputs per thread, pure registers ----
#pragma unroll
        for (int k = 0; k < R; ++k) {
            float acc = 0.f;
#pragma unroll
            for (int j = 0; j < KS; ++j) acc += w[j] * win[k + j];
            vbuf[k][t] = acc;                    // lane=col -> 2-way banks (free)
        }
        __syncthreads();

        // ---- h-conv: row hr = t>>5, cols 7*hs .. 7*hs+6 ----
        // reads vbuf[hr][7*hs+2+q]: banks (hr + 7*hs + q) % 32 -> exactly 2-way
        {
            const int hr = t >> 5, hs = t & 31;
            float hw[27];
#pragma unroll
            for (int q = 0; q < 27; ++q) hw[q] = vbuf[hr][7 * hs + 2 + q];
#pragma unroll
            for (int i = 0; i < 7; ++i) {
                float acc = 0.f;
#pragma unroll
                for (int j = 0; j < KS; ++j) acc += w[j] * hw[i + j];
                hbuf[hr][7 * hs + i] = acc;
            }
        }
        __syncthreads();

        // ---- out: lane=col re-read of hbuf -> fully coalesced stores ----
        if (t < TX && x0 + t < W) {
            const int gx = x0 + t;
#pragma unroll
            for (int k = 0; k < R; ++k)
                outp[((y0 + 8 * s + k) << 10) + gx] = hbuf[k][t];
        }

        // slide the vertical window by R
#pragma unroll
        for (int q = 0; q < WIN - R; ++q) win[q] = win[q + R];
    }
}

extern "C" void kernel_launch(void* const* d_in, const int* in_sizes, int n_in,
                              void* d_out, int out_size, void* d_ws, size_t ws_size,
                              hipStream_t stream) {
    const float* x = (const float*)d_in[0];
    const float* k = (const float*)d_in[1];
    float* out = (float*)d_out;
    const int n = in_sizes[0] / (H * W);  // batch*channels = 32
    dim3 grid(NXB, H / YO, n);            // 5 x 8 x 32 = 1280 blocks = 5/CU exactly
    gauss_fused<<<grid, dim3(256), 0, stream>>>(x, k, out);
}

// Round 4
// 246.842 us; speedup vs baseline: 1.5178x; 1.0092x over previous
//
#include <hip/hip_runtime.h>

#define H 1024
#define W 1024
#define KS 21
#define RAD 10
#define TX 224            // output cols per block (256 staged cols, 1/thread)
#define NXB 5             // 5*224 = 1120 >= 1024; last block masks
#define YO 128            // output rows per block
#define R 16              // rows per step
#define NSTEP (YO / R)    // 8
#define VSTR 257          // vbuf row stride (odd -> <=2-way banks everywhere)
#define HSTR 225          // hbuf row stride (odd)
#define WIN (KS + R - 1)  // 36-deep vertical register window

// jnp 'reflect' (no edge repeat) for indices in [-(W-1), 2W-2]
__device__ __forceinline__ int reflect1024(int i) {
    return 1023 - abs(1023 - abs(i));
}

__global__ __launch_bounds__(256, 4)
void gauss_fused(const float* __restrict__ in, const float* __restrict__ k2d,
                 float* __restrict__ out) {
    __shared__ float vbuf[R][VSTR];   // v-conv results, col j = global col x0-12+j
    __shared__ float hbuf[R][HSTR];   // h-conv results, col c = global col x0+c
    __shared__ float rw_s[KS];        // total 30932 B -> 5 blocks/CU

    const int t = threadIdx.x;
    const int x0 = blockIdx.x * TX;
    const int y0 = blockIdx.y * YO;
    const long long plane = (long long)blockIdx.z * (long long)(H * W);
    const float* inp = in + plane;
    float* outp = out + plane;

    // separable 1D factor: k2d = outer(r,r), r[i] = k2d[i][c]/sqrt(k2d[c][c])
    if (t < KS) {
        float c = k2d[RAD * KS + RAD];
        rw_s[t] = k2d[t * KS + RAD] / sqrtf(c);
    }
    __syncthreads();

    // wave-uniform weights -> SGPRs (v_fma takes one SGPR operand)
    float w[KS];
#pragma unroll
    for (int j = 0; j < KS; ++j)
        w[j] = __uint_as_float(__builtin_amdgcn_readfirstlane(__float_as_uint(rw_s[j])));

    // per-thread fixed input column; lane t -> global col x0-12+t (x-reflect folded once)
    const int xc = reflect1024(x0 - 12 + t);
    const float* colp = inp + xc;
    const bool yint = (y0 != 0) && (y0 != H - YO);   // interior y: no reflect needed

    // ---- preload: win rows y0-10 .. y0+9, prefetch rows y0+10 .. y0+25 ----
    float win[WIN];
#pragma unroll
    for (int q = 0; q < WIN - R; ++q)                // 20 rows
        win[q] = colp[reflect1024(y0 - RAD + q) << 10];
    float pf[R];
#pragma unroll
    for (int j = 0; j < R; ++j)
        pf[j] = colp[reflect1024(y0 + RAD + j) << 10];

#pragma unroll 1
    for (int s = 0; s < NSTEP; ++s) {
        // complete the 36-row window from last step's prefetch
#pragma unroll
        for (int j = 0; j < R; ++j) win[WIN - R + j] = pf[j];

        // issue next step's 16 loads now (~2 compute phases hide the latency)
        if (s < NSTEP - 1) {
            const int nbase = y0 + R * s + WIN - RAD;     // +26
            if (yint) {
                const float* p = colp + ((long long)nbase << 10);
#pragma unroll
                for (int j = 0; j < R; ++j) pf[j] = p[j << 10];
            } else {
#pragma unroll
                for (int j = 0; j < R; ++j) pf[j] = colp[reflect1024(nbase + j) << 10];
            }
        }

        // ---- v-conv: 16 outputs/thread, pure registers ----
#pragma unroll
        for (int k = 0; k < R; ++k) {
            float acc = 0.f;
#pragma unroll
            for (int j = 0; j < KS; ++j) acc += w[j] * win[k + j];
            vbuf[k][t] = acc;                  // banks (k+t)%32: 2-way, free
        }

        // ---- store previous step's results (barrier shadow) ----
        // hbuf(s-1) synced at barrier2(s-1); hconv(s) rewrites it only after barrier1
        if (s > 0 && t < TX && x0 + t < W) {
            const int ybase = y0 + R * (s - 1);
#pragma unroll
            for (int k = 0; k < R; ++k)
                outp[((ybase + k) << 10) + (x0 + t)] = hbuf[k][t];
        }
        __syncthreads();   // barrier1: vbuf ready; all stores of s-1 issued

        // ---- h-conv: row hr = t>>4 (0..15), cols 14*hs .. 14*hs+13 ----
        // reads vbuf[hr][14hs+2+q]: banks (hr+14hs+2+q)%32 -> <=2-way, free
        {
            const int hr = t >> 4, hs = t & 15;
            const int base = 14 * hs;
            float hw[34];
#pragma unroll
            for (int q = 0; q < 34; ++q) hw[q] = vbuf[hr][base + 2 + q];
#pragma unroll
            for (int i = 0; i < 14; ++i) {
                float acc = 0.f;
#pragma unroll
                for (int j = 0; j < KS; ++j) acc += w[j] * hw[i + j];
                hbuf[hr][base + i] = acc;      // banks (hr+14hs+i)%32: <=2-way
            }
        }
        __syncthreads();   // barrier2: hconv vbuf-reads done (next vconv may rewrite),
                           //           hbuf complete for the out-phase of step s+1

        // slide the vertical window by R
#pragma unroll
        for (int q = 0; q < WIN - R; ++q) win[q] = win[q + R];
    }

    // ---- flush: store the last step's results ----
    if (t < TX && x0 + t < W) {
        const int ybase = y0 + YO - R;
#pragma unroll
        for (int k = 0; k < R; ++k)
            outp[((ybase + k) << 10) + (x0 + t)] = hbuf[k][t];
    }
}

extern "C" void kernel_launch(void* const* d_in, const int* in_sizes, int n_in,
                              void* d_out, int out_size, void* d_ws, size_t ws_size,
                              hipStream_t stream) {
    const float* x = (const float*)d_in[0];
    const float* k = (const float*)d_in[1];
    float* out = (float*)d_out;
    const int n = in_sizes[0] / (H * W);  // batch*channels = 32
    dim3 grid(NXB, H / YO, n);            // 5 x 8 x 32 = 1280 blocks = 5/CU exactly
    gauss_fused<<<grid, dim3(256), 0, stream>>>(x, k, out);
}